// Round 1
// 816.815 us; speedup vs baseline: 1.0355x; 1.0355x over previous
//
#include <hip/hip_runtime.h>

typedef _Float16 half_t;
typedef __attribute__((ext_vector_type(4))) _Float16 half4;
typedef __attribute__((ext_vector_type(8))) _Float16 half8;
typedef __attribute__((ext_vector_type(4))) float f32x4;

#define WS_W1   0                          // 768*256 fp16 = 393216 B
#define WS_W2   (768*256*2)                // 256*256 fp16 = 131072 B
#define WS_BIAS (WS_W2 + 256*256*2)        // 8*4096 fp32 (C-fragment permuted)
#define QK_SCALE 0.17677669529663687f      // 32^-0.5

// ---------------- prep: weight fp32->fp16 + rpb bias gather (permuted) ----------------
__global__ __launch_bounds__(256) void prep_kernel(
    const float* __restrict__ qkv_w, const float* __restrict__ proj_w,
    const float* __restrict__ rpb, const int* __restrict__ rel_idx,
    char* __restrict__ ws) {
  int tid = blockIdx.x * 256 + threadIdx.x;
  half_t* W1 = (half_t*)(ws + WS_W1);
  half_t* W2 = (half_t*)(ws + WS_W2);
  float* BIASP = (float*)(ws + WS_BIAS);
  if (tid < 768 * 256) {
    int n = tid >> 8;
    float v = qkv_w[tid];
    if (n < 256) v *= QK_SCALE;          // fold q-scale into Wq
    W1[tid] = (half_t)v;
  }
  if (tid < 256 * 256) W2[tid] = (half_t)proj_w[tid];
  if (tid < 8 * 4096) {
    int r   = tid & 3;
    int l16 = (tid >> 2) & 15;
    int q   = (tid >> 6) & 3;
    int nt  = (tid >> 8) & 3;
    int mt  = (tid >> 10) & 3;
    int h   = (tid >> 12) & 7;
    int i = 16 * mt + 4 * q + r;
    int j = 16 * nt + l16;
    BIASP[tid] = rpb[rel_idx[i * 64 + j] * 8 + h];
  }
}

// QKV sub-GEMM: 64 tokens x 32 output dims (2 n-tiles), K=256.
__device__ __forceinline__ void qkv_gemm(const half_t* Xs, const half_t* W1,
                                         int n0, int l16, int quad,
                                         f32x4 acc[2][4]) {
#pragma unroll
  for (int ks = 0; ks < 8; ++ks) {
    half8 af[4];
#pragma unroll
    for (int mt = 0; mt < 4; ++mt)
      af[mt] = *(const half8*)(&Xs[(16 * mt + l16) * 264 + 32 * ks + quad * 8]);
#pragma unroll
    for (int nt = 0; nt < 2; ++nt) {
      half8 bf = *(const half8*)(&W1[(size_t)(n0 + 16 * nt + l16) * 256 + 32 * ks + quad * 8]);
#pragma unroll
      for (int mt = 0; mt < 4; ++mt)
        acc[nt][mt] = __builtin_amdgcn_mfma_f32_16x16x32_f16(af[mt], bf, acc[nt][mt], 0, 0, 0);
    }
  }
}

// ---------------- fused kernel: per-head dataflow, 2 blocks/CU ----------------
// LDS: 33792 + 8704 + 36864 = 79360 B  -> two 512-thread blocks co-resident per CU.
// Wave h owns head h end-to-end: V,Q,K sub-GEMMs -> wave-private scratch transpose
// -> S -> softmax -> PV, with NO barriers inside (only 3 barriers total).
__global__ __launch_bounds__(512, 4) void fused_kernel(
    const float* __restrict__ x, const float* __restrict__ mask,
    const float* __restrict__ qkv_b, const float* __restrict__ proj_b,
    const char* __restrict__ ws, float* __restrict__ out, int nW) {
  __shared__ __align__(16) half_t Xs[64 * 264];   // x fp16; reused as AO after barrier
  __shared__ __align__(16) half_t Ms[64 * 68];    // mask fp16
  __shared__ __align__(16) half_t Scr[8][2304];   // per-wave scratch (V^T / Q / K / P serially)

  const int b = blockIdx.x;
  const int tid = threadIdx.x;
  const int wave = tid >> 6, lane = tid & 63;
  const int l16 = lane & 15, quad = lane >> 4;
  const f32x4 z4 = {0.f, 0.f, 0.f, 0.f};
  const half_t* W1 = (const half_t*)(ws + WS_W1);
  half_t* Sw = &Scr[wave][0];

  // ---- phase 0: stage x (fp32->fp16) and mask into LDS, coalesced float4 ----
  {
    const float4* xw = (const float4*)(x + (size_t)b * 16384);
#pragma unroll
    for (int i = 0; i < 8; ++i) {
      int idx4 = tid + i * 512;
      float4 v = xw[idx4];
      int e = idx4 << 2;
      int row = e >> 8, col = e & 255;
      half4 pk;
      pk[0] = (half_t)v.x; pk[1] = (half_t)v.y; pk[2] = (half_t)v.z; pk[3] = (half_t)v.w;
      *(half4*)(&Xs[row * 264 + col]) = pk;
    }
    const float4* mw = (const float4*)(mask + (size_t)(b % nW) * 4096);
#pragma unroll
    for (int i = 0; i < 2; ++i) {
      int idx4 = tid + i * 512;
      float4 v = mw[idx4];
      int e = idx4 << 2;
      int mi = e >> 6, mj = e & 63;
      half4 pk;
      pk[0] = (half_t)v.x; pk[1] = (half_t)v.y; pk[2] = (half_t)v.z; pk[3] = (half_t)v.w;
      *(half4*)(&Ms[mi * 68 + mj]) = pk;
    }
  }
  __syncthreads();

  const int h = wave;
  half8 vf[2][2];          // entire V (32x64) of this head, B-fragment layout
  half8 qf[4];
  f32x4 S[4][4];
  f32x4 O[4][2];
  float linv[4][4];

  // ---- V pass: V = X @ Wv^T + b; stage V^T [d][t] (stride 72, packed b64) -> vf ----
  {
    f32x4 acc[2][4];
#pragma unroll
    for (int nt = 0; nt < 2; ++nt)
#pragma unroll
      for (int mt = 0; mt < 4; ++mt) acc[nt][mt] = z4;
    const int n0 = 512 + 32 * h;
    qkv_gemm(Xs, W1, n0, l16, quad, acc);
#pragma unroll
    for (int nt = 0; nt < 2; ++nt) {
      float vb = qkv_b[n0 + 16 * nt + l16];
#pragma unroll
      for (int mt = 0; mt < 4; ++mt) {
        half4 pk;
#pragma unroll
        for (int r = 0; r < 4; ++r) pk[r] = (half_t)(acc[nt][mt][r] + vb);
        *(half4*)(&Sw[(16 * nt + l16) * 72 + 16 * mt + 4 * quad]) = pk;
      }
    }
#pragma unroll
    for (int nt = 0; nt < 2; ++nt)
#pragma unroll
      for (int ks = 0; ks < 2; ++ks)
        vf[nt][ks] = *(const half8*)(&Sw[(16 * nt + l16) * 72 + 32 * ks + quad * 8]);
    asm volatile("s_waitcnt lgkmcnt(0)" ::: "memory");  // vf landed before scratch reuse
  }

  // ---- Q pass: stage [t][d] stride 36 (conflict-free writes) -> qf ----
  {
    f32x4 acc[2][4];
#pragma unroll
    for (int nt = 0; nt < 2; ++nt)
#pragma unroll
      for (int mt = 0; mt < 4; ++mt) acc[nt][mt] = z4;
    const int n0 = 32 * h;
    qkv_gemm(Xs, W1, n0, l16, quad, acc);
#pragma unroll
    for (int nt = 0; nt < 2; ++nt) {
      float qb = qkv_b[n0 + 16 * nt + l16] * QK_SCALE;
#pragma unroll
      for (int mt = 0; mt < 4; ++mt)
#pragma unroll
        for (int r = 0; r < 4; ++r)
          Sw[(16 * mt + 4 * quad + r) * 36 + 16 * nt + l16] = (half_t)(acc[nt][mt][r] + qb);
    }
#pragma unroll
    for (int mt = 0; mt < 4; ++mt) {
      union { half8 v; half4 hh[2]; } u;
      u.hh[0] = *(const half4*)(&Sw[(16 * mt + l16) * 36 + quad * 8]);
      u.hh[1] = *(const half4*)(&Sw[(16 * mt + l16) * 36 + quad * 8 + 4]);
      qf[mt] = u.v;
    }
    asm volatile("s_waitcnt lgkmcnt(0)" ::: "memory");  // qf landed before K overwrites
  }

  // ---- K pass + S = Q K^T (two K-tile halves to bound register pressure) ----
  {
    f32x4 acc[2][4];
#pragma unroll
    for (int nt = 0; nt < 2; ++nt)
#pragma unroll
      for (int mt = 0; mt < 4; ++mt) acc[nt][mt] = z4;
    const int n0 = 256 + 32 * h;
    qkv_gemm(Xs, W1, n0, l16, quad, acc);
#pragma unroll
    for (int nt = 0; nt < 2; ++nt) {
      float kb = qkv_b[n0 + 16 * nt + l16];
#pragma unroll
      for (int mt = 0; mt < 4; ++mt)
#pragma unroll
        for (int r = 0; r < 4; ++r)
          Sw[(16 * mt + 4 * quad + r) * 36 + 16 * nt + l16] = (half_t)(acc[nt][mt][r] + kb);
    }
#pragma unroll
    for (int kh = 0; kh < 2; ++kh) {
      half8 kf[2];
#pragma unroll
      for (int n2 = 0; n2 < 2; ++n2) {
        int jt = 2 * kh + n2;
        union { half8 v; half4 hh[2]; } u;
        u.hh[0] = *(const half4*)(&Sw[(16 * jt + l16) * 36 + quad * 8]);
        u.hh[1] = *(const half4*)(&Sw[(16 * jt + l16) * 36 + quad * 8 + 4]);
        kf[n2] = u.v;
      }
#pragma unroll
      for (int mt = 0; mt < 4; ++mt)
#pragma unroll
        for (int n2 = 0; n2 < 2; ++n2)
          S[mt][2 * kh + n2] =
              __builtin_amdgcn_mfma_f32_16x16x32_f16(qf[mt], kf[n2], z4, 0, 0, 0);
    }
    asm volatile("s_waitcnt lgkmcnt(0)" ::: "memory");  // kf landed before P overwrites
  }

  // ---- bias + mask + softmax + PV, per 16-row tile; P round-trips through scratch ----
  {
    const float4* BP4 = (const float4*)(ws + WS_BIAS);
#pragma unroll
    for (int mt = 0; mt < 4; ++mt) {
#pragma unroll
      for (int nt = 0; nt < 4; ++nt) {
        float4 bv = BP4[(size_t)(((h * 4 + mt) * 4 + nt) * 64) + quad * 16 + l16];
#pragma unroll
        for (int r = 0; r < 4; ++r)
          S[mt][nt][r] += ((const float*)&bv)[r] +
                          (float)Ms[(16 * mt + 4 * quad + r) * 68 + 16 * nt + l16];
      }
#pragma unroll
      for (int r = 0; r < 4; ++r) {
        float mx = fmaxf(fmaxf(S[mt][0][r], S[mt][1][r]), fmaxf(S[mt][2][r], S[mt][3][r]));
#pragma unroll
        for (int o = 1; o < 16; o <<= 1) mx = fmaxf(mx, __shfl_xor(mx, o, 64));
        float s = 0.f;
#pragma unroll
        for (int nt = 0; nt < 4; ++nt) {
          float e = exp2f((S[mt][nt][r] - mx) * 1.44269504f);
          S[mt][nt][r] = e;
          s += e;
        }
#pragma unroll
        for (int o = 1; o < 16; o <<= 1) s += __shfl_xor(s, o, 64);
        linv[mt][r] = __builtin_amdgcn_rcpf(s);  // normalize O at the end instead of P
      }
      // unnormalized P tile [16][64] stride 72
#pragma unroll
      for (int nt = 0; nt < 4; ++nt)
#pragma unroll
        for (int r = 0; r < 4; ++r)
          Sw[(4 * quad + r) * 72 + 16 * nt + l16] = (half_t)S[mt][nt][r];
      f32x4 o0 = z4, o1 = z4;
#pragma unroll
      for (int ks = 0; ks < 2; ++ks) {
        half8 pf = *(const half8*)(&Sw[l16 * 72 + 32 * ks + quad * 8]);
        o0 = __builtin_amdgcn_mfma_f32_16x16x32_f16(pf, vf[0][ks], o0, 0, 0, 0);
        o1 = __builtin_amdgcn_mfma_f32_16x16x32_f16(pf, vf[1][ks], o1, 0, 0, 0);
      }
#pragma unroll
      for (int r = 0; r < 4; ++r) {
        O[mt][0][r] = o0[r] * linv[mt][r];
        O[mt][1][r] = o1[r] * linv[mt][r];
      }
      asm volatile("s_waitcnt lgkmcnt(0)" ::: "memory");  // pf landed before next P tile
    }
  }
  __syncthreads();

  // ---- AO exchange: O -> Xs (head h -> cols [32h, 32h+32)) ----
#pragma unroll
  for (int mt = 0; mt < 4; ++mt)
#pragma unroll
    for (int nt = 0; nt < 2; ++nt)
#pragma unroll
      for (int r = 0; r < 4; ++r)
        Xs[(16 * mt + 4 * quad + r) * 264 + 32 * h + 16 * nt + l16] = (half_t)O[mt][nt][r];
  __syncthreads();

  // ---- proj: out = AO[64x256] @ W2^T + b ; wave w -> out-dims [32w, 32w+32) ----
  {
    const half_t* W2 = (const half_t*)(ws + WS_W2);
    const int nb = wave * 32;
    f32x4 C[2][4];
#pragma unroll
    for (int nt = 0; nt < 2; ++nt)
#pragma unroll
      for (int mt = 0; mt < 4; ++mt) C[nt][mt] = z4;
#pragma unroll
    for (int ks = 0; ks < 8; ++ks) {
      half8 af[4];
#pragma unroll
      for (int mt = 0; mt < 4; ++mt)
        af[mt] = *(const half8*)(&Xs[(16 * mt + l16) * 264 + 32 * ks + quad * 8]);
#pragma unroll
      for (int nt = 0; nt < 2; ++nt) {
        half8 bf = *(const half8*)(&W2[(size_t)(nb + 16 * nt + l16) * 256 + 32 * ks + quad * 8]);
#pragma unroll
        for (int mt = 0; mt < 4; ++mt)
          C[nt][mt] = __builtin_amdgcn_mfma_f32_16x16x32_f16(af[mt], bf, C[nt][mt], 0, 0, 0);
      }
    }
#pragma unroll
    for (int nt = 0; nt < 2; ++nt) {
      int c = nb + 16 * nt + l16;
      float pb = proj_b[c];
#pragma unroll
      for (int mt = 0; mt < 4; ++mt)
#pragma unroll
        for (int r = 0; r < 4; ++r) {
          int t = 16 * mt + 4 * quad + r;
          out[(size_t)b * 16384 + t * 256 + c] = C[nt][mt][r] + pb;
        }
    }
  }
}

extern "C" void kernel_launch(void* const* d_in, const int* in_sizes, int n_in,
                              void* d_out, int out_size, void* d_ws, size_t ws_size,
                              hipStream_t stream) {
  const float* x      = (const float*)d_in[0];
  const float* mask   = (const float*)d_in[1];
  const float* rpb    = (const float*)d_in[2];
  const float* qkv_w  = (const float*)d_in[3];
  const float* qkv_b  = (const float*)d_in[4];
  const float* proj_w = (const float*)d_in[5];
  const float* proj_b = (const float*)d_in[6];
  const int*   rel    = (const int*)d_in[7];
  float* out = (float*)d_out;
  char* ws = (char*)d_ws;
  int B_ = in_sizes[0] / 16384;   // windows*batch
  int nW = in_sizes[1] / 4096;    // mask windows
  hipLaunchKernelGGL(prep_kernel, dim3(768), dim3(256), 0, stream,
                     qkv_w, proj_w, rpb, rel, ws);
  hipLaunchKernelGGL(fused_kernel, dim3(B_), dim3(512), 0, stream,
                     x, mask, qkv_b, proj_b, (const char*)ws, out, nW);
}